// Round 6
// baseline (148.635 us; speedup 1.0000x reference)
//
#include <hip/hip_runtime.h>
#include <hip/hip_bf16.h>

// Problem constants (B=2, T=2048, C=1024, H=16, G=4, hd=64, KV=256, WINDOW=256)
#define TT 2048
#define CC 1024
#define KVD 256
#define QKVD 1536

typedef __bf16 bf16x8 __attribute__((ext_vector_type(8)));
typedef float f32x4 __attribute__((ext_vector_type(4)));

// async global->LDS, 16B per lane. LDS dest is wave-uniform base + lane*16 (HW rule).
__device__ __forceinline__ void gload_lds16(const __hip_bfloat16* g, __hip_bfloat16* l) {
  __builtin_amdgcn_global_load_lds(
      (const __attribute__((address_space(1))) unsigned int*)g,
      (__attribute__((address_space(3))) unsigned int*)l, 16, 0, 0);
}

// ---------------- merged prep: x->bf16 convert + weight packs + bias ----------------
// 1D grid: [0,4096) convert x; [4096,4480) pack wqkvT; [4480,4736) pack woT; [4736] bias.

__global__ __launch_bounds__(256) void k_prep(const float* __restrict__ x,
                                              const float* __restrict__ Wq,
                                              const float* __restrict__ Wk,
                                              const float* __restrict__ Wv,
                                              const float* __restrict__ Wo,
                                              const float* __restrict__ bq,
                                              const float* __restrict__ bk,
                                              const float* __restrict__ bv,
                                              __hip_bfloat16* __restrict__ xbf,
                                              __hip_bfloat16* __restrict__ wqkvT,
                                              __hip_bfloat16* __restrict__ woT,
                                              float* __restrict__ bqkv) {
  const int bxid = blockIdx.x;
  if (bxid < 4096) {
    size_t idx = ((size_t)bxid * 256 + threadIdx.x) * 4;
    float4 v = *(const float4*)(x + idx);
    xbf[idx + 0] = __float2bfloat16(v.x);
    xbf[idx + 1] = __float2bfloat16(v.y);
    xbf[idx + 2] = __float2bfloat16(v.z);
    xbf[idx + 3] = __float2bfloat16(v.w);
    return;
  }
  if (bxid == 4736) {
    for (int i = threadIdx.x; i < 1536; i += 256) {
      float v;
      if (i < 1024)      v = bq[i];
      else if (i < 1280) v = bk[i - 1024];
      else               v = bv[i - 1280];
      bqkv[i] = v;
    }
    return;
  }
  // weight pack via LDS tile transpose, coalesced both sides
  __shared__ float tile[64][65];
  const float* src;
  int ncols, k0, n0;
  __hip_bfloat16* dst;
  if (bxid < 4480) {
    const int idx = bxid - 4096;          // 384 tiles: 16 k x 24 n
    k0 = (idx & 15) * 64;
    n0 = (idx >> 4) * 64;
    dst = wqkvT;
    if (n0 < 1024)      { src = Wq; ncols = 1024; }
    else if (n0 < 1280) { src = Wk - 1024; ncols = 256; }
    else                { src = Wv - 1280; ncols = 256; }
  } else {
    const int idx = bxid - 4480;          // 256 tiles: 16 k x 16 n
    k0 = (idx & 15) * 64;
    n0 = (idx >> 4) * 64;
    dst = woT; src = Wo; ncols = 1024;
  }
  const int rw = threadIdx.x >> 6;
  const int cl = threadIdx.x & 63;
#pragma unroll
  for (int i = 0; i < 16; ++i) {
    const int kr = rw + i * 4;
    tile[kr][cl] = src[(size_t)(k0 + kr) * ncols + n0 + cl];
  }
  __syncthreads();
#pragma unroll
  for (int i = 0; i < 16; ++i) {
    const int nr = rw + i * 4;
    dst[(size_t)(n0 + nr) * 1024 + k0 + cl] = __float2bfloat16(tile[cl][nr]);
  }
}

// ---------------- gemm1: QKV projection, 128x128 tile, BK=64, 8 waves, dbuf -------
// v6: double-buffered LDS prefetch (attn-v4's proven pattern): issue stage for
// tile t+1 BEFORE computing tile t; one barrier per K-step. Load latency hides
// under 128 MFMA instead of being fully exposed at a stage->drain->compute chain.
// grid (1536/128, 4096/128) = (12, 32).

__global__ __launch_bounds__(512, 2) void k_gemm1(const __hip_bfloat16* __restrict__ A,
                                                  const __hip_bfloat16* __restrict__ BT,
                                                  const float* __restrict__ bias,
                                                  __hip_bfloat16* __restrict__ C,
                                                  __hip_bfloat16* __restrict__ vtg) {
  __shared__ __hip_bfloat16 As[2][128][64];   // 32 KB
  __shared__ __hip_bfloat16 Bs[2][128][64];   // 32 KB

  const int tid  = threadIdx.x;
  const int m0   = blockIdx.y * 128;
  const int n0   = blockIdx.x * 128;
  const int w    = tid >> 6;               // 0..7
  const int lane = tid & 63;
  const int quad = lane >> 4;
  const int l16  = lane & 15;
  const int wm   = (w & 3) * 32;           // 4 row-groups of 32
  const int wn   = (w >> 2) * 64;          // 2 col-groups of 64

  const int dl_r = lane >> 3;               // 0..7
  const int dl_c = (lane & 7) ^ dl_r;       // swizzled global 16B chunk

  // wave w stages A rows [w*16, w*16+16) and B rows [w*16, w*16+16)
  const __hip_bfloat16* gA = A + (size_t)(m0 + w * 16 + dl_r) * 1024 + dl_c * 8;
  const __hip_bfloat16* gB = BT + (size_t)(n0 + w * 16 + dl_r) * 1024 + dl_c * 8;

  f32x4 acc[2][4] = {};

  // prologue: stage kt=0 into buf 0
  gload_lds16(gA,                    &As[0][w * 16][0]);
  gload_lds16(gA + (size_t)8 * 1024, &As[0][w * 16 + 8][0]);
  gload_lds16(gB,                    &Bs[0][w * 16][0]);
  gload_lds16(gB + (size_t)8 * 1024, &Bs[0][w * 16 + 8][0]);

  int buf = 0;
  for (int kt = 0; kt < 16; ++kt) {
    __syncthreads();  // drains loads for buf[cur]; joins all waves post-compute
    if (kt < 15) {
      const int kn = (kt + 1) << 6;
      gload_lds16(gA + kn,                    &As[buf ^ 1][w * 16][0]);
      gload_lds16(gA + kn + (size_t)8 * 1024, &As[buf ^ 1][w * 16 + 8][0]);
      gload_lds16(gB + kn,                    &Bs[buf ^ 1][w * 16][0]);
      gload_lds16(gB + kn + (size_t)8 * 1024, &Bs[buf ^ 1][w * 16 + 8][0]);
    }

#pragma unroll
    for (int ks = 0; ks < 2; ++ks) {
      const int cb = (ks << 2) + quad;
      bf16x8 fa[2], fb[4];
#pragma unroll
      for (int i = 0; i < 2; ++i)
        fa[i] = *(const bf16x8*)&As[buf][wm + i * 16 + l16][(cb ^ (l16 & 7)) << 3];
#pragma unroll
      for (int j = 0; j < 4; ++j)
        fb[j] = *(const bf16x8*)&Bs[buf][wn + j * 16 + l16][(cb ^ (l16 & 7)) << 3];
#pragma unroll
      for (int i = 0; i < 2; ++i)
#pragma unroll
        for (int j = 0; j < 4; ++j)
          acc[i][j] = __builtin_amdgcn_mfma_f32_16x16x32_bf16(fa[i], fb[j], acc[i][j], 0, 0, 0);
    }
    buf ^= 1;
  }

  // epilogue: C/D layout col=lane&15, row=quad*4+reg. 1280 boundary is wave-uniform.
#pragma unroll
  for (int j = 0; j < 4; ++j) {
    const int gn = n0 + wn + j * 16 + l16;
    const float bias_v = bias[gn];
    if (gn >= 1280) {
      // V column: write transposed into vtg[(b*4+g)*64 + d][t]
      const int dfull = gn - 1280;
      const int gg = dfull >> 6;
      const int dd = dfull & 63;
#pragma unroll
      for (int i = 0; i < 2; ++i) {
        const int gm = m0 + wm + i * 16 + quad * 4;  // 4 consecutive tokens
        const int bb = gm >> 11;
        const int tl = gm & 2047;
        __hip_bfloat16 tmp[4];
#pragma unroll
        for (int r = 0; r < 4; ++r) tmp[r] = __float2bfloat16(acc[i][j][r] + bias_v);
        *(uint2*)(vtg + ((size_t)((bb * 4 + gg) * 64 + dd)) * TT + tl) = *(const uint2*)tmp;
      }
    } else {
#pragma unroll
      for (int i = 0; i < 2; ++i) {
        const int gmb = m0 + wm + i * 16 + quad * 4;
#pragma unroll
        for (int r = 0; r < 4; ++r)
          C[(size_t)(gmb + r) * QKVD + gn] = __float2bfloat16(acc[i][j][r] + bias_v);
      }
    }
  }
}

// ---------------- gemm2: output projection, 64x128 tile, BK=64, 4 waves, dbuf -----
// v6: reverted to the proven 64x128 / 512-block shape (R5's 128x128 1-block/CU
// retile regressed: no cross-block overlap at barriers) + double-buffered prefetch
// as in gemm1. LDS 48 KB -> 3 blocks/CU cap, grid 2/CU. grid (8, 64) = 512 blocks.

__global__ __launch_bounds__(256, 3) void k_gemm2(const __hip_bfloat16* __restrict__ A,
                                                  const __hip_bfloat16* __restrict__ BT,
                                                  const float* __restrict__ bias,
                                                  float* __restrict__ C) {
  __shared__ __hip_bfloat16 As[2][64][64];    // 16 KB
  __shared__ __hip_bfloat16 Bs[2][128][64];   // 32 KB

  const int tid  = threadIdx.x;
  const int m0   = blockIdx.y * 64;
  const int n0   = blockIdx.x * 128;
  const int w    = tid >> 6;
  const int lane = tid & 63;
  const int quad = lane >> 4;
  const int l16  = lane & 15;
  const int wm   = (w >> 1) * 32;
  const int wn   = (w & 1) * 64;

  const int dl_r = lane >> 3;
  const int dl_c = (lane & 7) ^ dl_r;

  const __hip_bfloat16* gA = A + (size_t)(m0 + w * 16 + dl_r) * 1024 + dl_c * 8;
  const __hip_bfloat16* gB = BT + (size_t)(n0 + w * 32 + dl_r) * 1024 + dl_c * 8;

  f32x4 acc[2][4] = {};

  // prologue: stage kt=0 into buf 0
  gload_lds16(gA,                     &As[0][w * 16][0]);
  gload_lds16(gA + (size_t)8 * 1024,  &As[0][w * 16 + 8][0]);
  gload_lds16(gB,                     &Bs[0][w * 32][0]);
  gload_lds16(gB + (size_t)8 * 1024,  &Bs[0][w * 32 + 8][0]);
  gload_lds16(gB + (size_t)16 * 1024, &Bs[0][w * 32 + 16][0]);
  gload_lds16(gB + (size_t)24 * 1024, &Bs[0][w * 32 + 24][0]);

  int buf = 0;
  for (int kt = 0; kt < 16; ++kt) {
    __syncthreads();
    if (kt < 15) {
      const int kn = (kt + 1) << 6;
      gload_lds16(gA + kn,                     &As[buf ^ 1][w * 16][0]);
      gload_lds16(gA + kn + (size_t)8 * 1024,  &As[buf ^ 1][w * 16 + 8][0]);
      gload_lds16(gB + kn,                     &Bs[buf ^ 1][w * 32][0]);
      gload_lds16(gB + kn + (size_t)8 * 1024,  &Bs[buf ^ 1][w * 32 + 8][0]);
      gload_lds16(gB + kn + (size_t)16 * 1024, &Bs[buf ^ 1][w * 32 + 16][0]);
      gload_lds16(gB + kn + (size_t)24 * 1024, &Bs[buf ^ 1][w * 32 + 24][0]);
    }

#pragma unroll
    for (int ks = 0; ks < 2; ++ks) {
      const int cb = (ks << 2) + quad;
      bf16x8 fa[2], fb[4];
#pragma unroll
      for (int i = 0; i < 2; ++i)
        fa[i] = *(const bf16x8*)&As[buf][wm + i * 16 + l16][(cb ^ (l16 & 7)) << 3];
#pragma unroll
      for (int j = 0; j < 4; ++j)
        fb[j] = *(const bf16x8*)&Bs[buf][wn + j * 16 + l16][(cb ^ (l16 & 7)) << 3];
#pragma unroll
      for (int i = 0; i < 2; ++i)
#pragma unroll
        for (int j = 0; j < 4; ++j)
          acc[i][j] = __builtin_amdgcn_mfma_f32_16x16x32_bf16(fa[i], fb[j], acc[i][j], 0, 0, 0);
    }
    buf ^= 1;
  }

#pragma unroll
  for (int j = 0; j < 4; ++j) {
    const int gn = n0 + wn + j * 16 + l16;
    const float bias_v = bias[gn];
#pragma unroll
    for (int i = 0; i < 2; ++i) {
      const int gmb = m0 + wm + i * 16 + quad * 4;
#pragma unroll
      for (int r = 0; r < 4; ++r)
        C[(size_t)(gmb + r) * CC + gn] = acc[i][j][r] + bias_v;
    }
  }
}

// ---------------- MFMA flash attention v4: QBLK=128, 8 waves, 2x K/V reuse --------
// One K/V staging pass serves 128 q-rows; 50 KB LDS -> 16+ waves/CU; grid 512
// blocks = 2/CU fully resident. Block stages 6 key-chunks jc = i0-256 .. i0+64;
// wave-group wg = w>>2 active for cc in [wg, 4+wg], diagonal mask at cc==4+wg,
// window-tail mask at cc==wg. Small-bx clamp: cc_lo = max(0, 4-2*bx).

__global__ __launch_bounds__(512) void k_attn(const __hip_bfloat16* __restrict__ qkv,
                                              const __hip_bfloat16* __restrict__ vtg,
                                              __hip_bfloat16* __restrict__ y) {
  __shared__ __hip_bfloat16 Kb[2][64][64];  // [buf][key][d]   16 KB
  __shared__ __hip_bfloat16 Vb[2][64][64];  // [buf][d][key]   16 KB
  __shared__ __hip_bfloat16 Ps[8][16][72];  // per-wave P tile 18.4 KB

  const int t    = threadIdx.x;
  const int w    = t >> 6;      // 0..7
  const int lane = t & 63;
  const int quad = lane >> 4;
  const int l16  = lane & 15;
  const int bx   = blockIdx.x;  // 0..15
  const int h    = blockIdx.y;
  const int b    = blockIdx.z;
  const int g    = h >> 2;      // repeat_interleave: heads 4g..4g+3 -> group g
  const int i0   = bx * 128;
  const int wg   = w >> 2;      // wave-group: 0 = rows [i0,i0+64), 1 = [i0+64,i0+128)
  const int myq0 = i0 + w * 16;
  const int qrow      = myq0 + l16;
  const int my_q_base = myq0 + quad * 4;

  const int lrow = lane >> 3;
  const int cgl  = (lane & 7) ^ lrow;

  // wave w stages rows w*8 .. w*8+7 of each 64-row K/V chunk (1 gload each)
  const __hip_bfloat16* kg =
      qkv + ((size_t)(b * TT + w * 8 + lrow)) * QKVD + 1024 + g * 64 + cgl * 8;
  const __hip_bfloat16* vg =
      vtg + ((size_t)((b * 4 + g) * 64 + w * 8 + lrow)) * TT + cgl * 8;

  bf16x8 fq[2];
  {
    const __hip_bfloat16* qp = qkv + ((size_t)(b * TT + qrow)) * QKVD + h * 64 + quad * 8;
    fq[0] = *(const bf16x8*)qp;
    fq[1] = *(const bf16x8*)(qp + 32);
  }

  float l_r[4] = {0.f, 0.f, 0.f, 0.f};
  f32x4 o_acc[4] = {};
  const float EC = 0.125f * 1.44269504f;  // (1/sqrt(64)) * log2(e)

  const int cc_lo = bx >= 2 ? 0 : (4 - 2 * bx);
  const int jbase = i0 - 256;

  {
    const int jc = jbase + cc_lo * 64;
    gload_lds16(kg + (size_t)jc * QKVD, &Kb[0][w * 8][0]);
    gload_lds16(vg + jc,                &Vb[0][w * 8][0]);
  }

  int buf = 0;
  for (int cc = cc_lo; cc < 6; ++cc) {
    __syncthreads();
    if (cc < 5) {
      const int jn = jbase + (cc + 1) * 64;
      gload_lds16(kg + (size_t)jn * QKVD, &Kb[buf ^ 1][w * 8][0]);
      gload_lds16(vg + jn,                &Vb[buf ^ 1][w * 8][0]);
    }

    if (cc >= wg && cc <= 4 + wg) {   // this wave-group's 5-chunk window
      const int jc = jbase + cc * 64;

      f32x4 sacc[4] = {};
#pragma unroll
      for (int ks = 0; ks < 2; ++ks) {
        const int sw = (((ks << 2) + quad) ^ (l16 & 7)) << 3;
#pragma unroll
        for (int nt = 0; nt < 4; ++nt) {
          const bf16x8 fk = *(const bf16x8*)&Kb[buf][nt * 16 + l16][sw];
          sacc[nt] = __builtin_amdgcn_mfma_f32_16x16x32_bf16(fq[ks], fk, sacc[nt], 0, 0, 0);
        }
      }

      // p = exp(s/8); mask only where needed (wave-uniform chunk classification)
      if (cc == 4 + wg) {        // diagonal: key <= i
#pragma unroll
        for (int r = 0; r < 4; ++r) {
          const int gi = my_q_base + r;
#pragma unroll
          for (int nt = 0; nt < 4; ++nt) {
            const int key = jc + nt * 16 + l16;
            const float p = (key <= gi) ? exp2f(sacc[nt][r] * EC) : 0.f;
            l_r[r] += p;
            Ps[w][quad * 4 + r][nt * 16 + l16] = __float2bfloat16(p);
          }
        }
      } else if (cc == wg) {     // window tail: key >= i - 256 (only reachable when jc>=0)
#pragma unroll
        for (int r = 0; r < 4; ++r) {
          const int glo = my_q_base + r - 256;
#pragma unroll
          for (int nt = 0; nt < 4; ++nt) {
            const int key = jc + nt * 16 + l16;
            const float p = (key >= glo) ? exp2f(sacc[nt][r] * EC) : 0.f;
            l_r[r] += p;
            Ps[w][quad * 4 + r][nt * 16 + l16] = __float2bfloat16(p);
          }
        }
      } else {                   // interior: mask-free
#pragma unroll
        for (int r = 0; r < 4; ++r)
#pragma unroll
          for (int nt = 0; nt < 4; ++nt) {
            const float p = exp2f(sacc[nt][r] * EC);
            l_r[r] += p;
            Ps[w][quad * 4 + r][nt * 16 + l16] = __float2bfloat16(p);
          }
      }

      const bf16x8 fp0 = *(const bf16x8*)&Ps[w][l16][quad * 8];
      const bf16x8 fp1 = *(const bf16x8*)&Ps[w][l16][32 + quad * 8];

#pragma unroll
      for (int ks = 0; ks < 2; ++ks) {
        const int sw = (((ks << 2) + quad) ^ (l16 & 7)) << 3;
#pragma unroll
        for (int jt = 0; jt < 4; ++jt) {
          const bf16x8 fv = *(const bf16x8*)&Vb[buf][jt * 16 + l16][sw];
          o_acc[jt] = __builtin_amdgcn_mfma_f32_16x16x32_bf16(ks == 0 ? fp0 : fp1, fv,
                                                              o_acc[jt], 0, 0, 0);
        }
      }
    }
    buf ^= 1;
  }

#pragma unroll
  for (int r = 0; r < 4; ++r) {
#pragma unroll
    for (int d = 1; d < 16; d <<= 1) l_r[r] += __shfl_xor(l_r[r], d);
    const float inv = 1.f / l_r[r];
    __hip_bfloat16* yp = y + ((size_t)(b * TT + my_q_base + r)) * CC + h * 64 + l16;
#pragma unroll
    for (int jt = 0; jt < 4; ++jt)
      yp[jt * 16] = __float2bfloat16(o_acc[jt][r] * inv);
  }
}

// ---------------- launch ----------------

extern "C" void kernel_launch(void* const* d_in, const int* in_sizes, int n_in,
                              void* d_out, int out_size, void* d_ws, size_t ws_size,
                              hipStream_t stream) {
  const float* x  = (const float*)d_in[0];
  const float* Wq = (const float*)d_in[1];
  const float* bq = (const float*)d_in[2];
  const float* Wk = (const float*)d_in[3];
  const float* bk = (const float*)d_in[4];
  const float* Wv = (const float*)d_in[5];
  const float* bv = (const float*)d_in[6];
  const float* Wo = (const float*)d_in[7];
  const float* bo = (const float*)d_in[8];
  float* out = (float*)d_out;

  char* ws = (char*)d_ws;
  const size_t M = 2 * TT;  // 4096
  __hip_bfloat16* xbf   = (__hip_bfloat16*)(ws);               // 8 MB
  __hip_bfloat16* qkv   = (__hip_bfloat16*)(ws + 8388608);     // 12 MB (V region unused)
  __hip_bfloat16* ybf   = (__hip_bfloat16*)(ws + 20971520);    // 8 MB
  __hip_bfloat16* wqkvT = (__hip_bfloat16*)(ws + 29360128);    // 3 MB
  __hip_bfloat16* woT   = (__hip_bfloat16*)(ws + 32505856);    // 2 MB
  float*          bqkv  = (float*)(ws + 34603008);             // 6 KB
  __hip_bfloat16* vtg   = (__hip_bfloat16*)(ws + 34609152);    // 2 MB

  // prep: x convert (4096) + wqkv pack (384) + wo pack (256) + bias (1)
  k_prep<<<4737, 256, 0, stream>>>(x, Wq, Wk, Wv, Wo, bq, bk, bv,
                                   xbf, wqkvT, woT, bqkv);

  // QKV projection: 128x128 tiles, 8-wave blocks, dbuf prefetch, grid (12, 32)
  k_gemm1<<<dim3(QKVD / 128, M / 128), 512, 0, stream>>>(xbf, wqkvT, bqkv, qkv, vtg);

  // attention: 512 blocks of 512 threads (8 waves, QBLK=128)
  k_attn<<<dim3(TT / 128, 16, 2), 512, 0, stream>>>(qkv, vtg, ybf);

  // output projection: 64x128 tiles, 4-wave blocks, dbuf prefetch, grid (8, 64)
  k_gemm2<<<dim3(CC / 128, M / 64), 256, 0, stream>>>(ybf, woT, bo, out);
}

// Round 7
// 142.749 us; speedup vs baseline: 1.0412x; 1.0412x over previous
//
#include <hip/hip_runtime.h>
#include <hip/hip_bf16.h>

// Problem constants (B=2, T=2048, C=1024, H=16, G=4, hd=64, KV=256, WINDOW=256)
#define TT 2048
#define CC 1024
#define KVD 256
#define QKVD 1536

typedef __bf16 bf16x8 __attribute__((ext_vector_type(8)));
typedef float f32x4 __attribute__((ext_vector_type(4)));

// async global->LDS, 16B per lane. LDS dest is wave-uniform base + lane*16 (HW rule).
__device__ __forceinline__ void gload_lds16(const __hip_bfloat16* g, __hip_bfloat16* l) {
  __builtin_amdgcn_global_load_lds(
      (const __attribute__((address_space(1))) unsigned int*)g,
      (__attribute__((address_space(3))) unsigned int*)l, 16, 0, 0);
}

// ---------------- merged prep: x->bf16 convert + weight packs + bias ----------------
// 1D grid: [0,4096) convert x; [4096,4480) pack wqkvT; [4480,4736) pack woT; [4736] bias.

__global__ __launch_bounds__(256) void k_prep(const float* __restrict__ x,
                                              const float* __restrict__ Wq,
                                              const float* __restrict__ Wk,
                                              const float* __restrict__ Wv,
                                              const float* __restrict__ Wo,
                                              const float* __restrict__ bq,
                                              const float* __restrict__ bk,
                                              const float* __restrict__ bv,
                                              __hip_bfloat16* __restrict__ xbf,
                                              __hip_bfloat16* __restrict__ wqkvT,
                                              __hip_bfloat16* __restrict__ woT,
                                              float* __restrict__ bqkv) {
  const int bxid = blockIdx.x;
  if (bxid < 4096) {
    size_t idx = ((size_t)bxid * 256 + threadIdx.x) * 4;
    float4 v = *(const float4*)(x + idx);
    xbf[idx + 0] = __float2bfloat16(v.x);
    xbf[idx + 1] = __float2bfloat16(v.y);
    xbf[idx + 2] = __float2bfloat16(v.z);
    xbf[idx + 3] = __float2bfloat16(v.w);
    return;
  }
  if (bxid == 4736) {
    for (int i = threadIdx.x; i < 1536; i += 256) {
      float v;
      if (i < 1024)      v = bq[i];
      else if (i < 1280) v = bk[i - 1024];
      else               v = bv[i - 1280];
      bqkv[i] = v;
    }
    return;
  }
  // weight pack via LDS tile transpose, coalesced both sides
  __shared__ float tile[64][65];
  const float* src;
  int ncols, k0, n0;
  __hip_bfloat16* dst;
  if (bxid < 4480) {
    const int idx = bxid - 4096;          // 384 tiles: 16 k x 24 n
    k0 = (idx & 15) * 64;
    n0 = (idx >> 4) * 64;
    dst = wqkvT;
    if (n0 < 1024)      { src = Wq; ncols = 1024; }
    else if (n0 < 1280) { src = Wk - 1024; ncols = 256; }
    else                { src = Wv - 1280; ncols = 256; }
  } else {
    const int idx = bxid - 4480;          // 256 tiles: 16 k x 16 n
    k0 = (idx & 15) * 64;
    n0 = (idx >> 4) * 64;
    dst = woT; src = Wo; ncols = 1024;
  }
  const int rw = threadIdx.x >> 6;
  const int cl = threadIdx.x & 63;
#pragma unroll
  for (int i = 0; i < 16; ++i) {
    const int kr = rw + i * 4;
    tile[kr][cl] = src[(size_t)(k0 + kr) * ncols + n0 + cl];
  }
  __syncthreads();
#pragma unroll
  for (int i = 0; i < 16; ++i) {
    const int nr = rw + i * 4;
    dst[(size_t)(n0 + nr) * 1024 + k0 + cl] = __float2bfloat16(tile[cl][nr]);
  }
}

// ---------------- gemm1: QKV projection, 128x128 tile, BK=64, 8 waves -------------
// K-loop: R4's proven single-buffer 2-barrier form (dbuf regressed in R6).
// v7: coalesced Q/K epilogue — per-wave LDS transpose (staging buffer is dead after
// the loop), then b128 reads + 16B/lane coalesced stores (32 scalar 2B stores -> 4
// dwordx4 per lane). V columns (blocks bx>=10, wave-uniform) keep the transposed
// vtg uint2 path. grid (12, 32).

__global__ __launch_bounds__(512, 4) void k_gemm1(const __hip_bfloat16* __restrict__ A,
                                                  const __hip_bfloat16* __restrict__ BT,
                                                  const float* __restrict__ bias,
                                                  __hip_bfloat16* __restrict__ C,
                                                  __hip_bfloat16* __restrict__ vtg) {
  __shared__ __hip_bfloat16 S[2][128][64];   // S[0]=As, S[1]=Bs, 32 KB contiguous

  const int tid  = threadIdx.x;
  const int m0   = blockIdx.y * 128;
  const int n0   = blockIdx.x * 128;
  const int w    = tid >> 6;               // 0..7
  const int lane = tid & 63;
  const int quad = lane >> 4;
  const int l16  = lane & 15;
  const int wm   = (w & 3) * 32;           // 4 row-groups of 32
  const int wn   = (w >> 2) * 64;          // 2 col-groups of 64

  const int dl_r = lane >> 3;               // 0..7
  const int dl_c = (lane & 7) ^ dl_r;       // swizzled global 16B chunk

  // wave w stages A rows [w*16, w*16+16) and B rows [w*16, w*16+16)
  const __hip_bfloat16* gA = A + (size_t)(m0 + w * 16 + dl_r) * 1024 + dl_c * 8;
  const __hip_bfloat16* gB = BT + (size_t)(n0 + w * 16 + dl_r) * 1024 + dl_c * 8;

  f32x4 acc[2][4] = {};

  for (int kt = 0; kt < 16; ++kt) {
    const int k0 = kt << 6;
    gload_lds16(gA + k0,                    &S[0][w * 16][0]);
    gload_lds16(gA + k0 + (size_t)8 * 1024, &S[0][w * 16 + 8][0]);
    gload_lds16(gB + k0,                    &S[1][w * 16][0]);
    gload_lds16(gB + k0 + (size_t)8 * 1024, &S[1][w * 16 + 8][0]);
    __syncthreads();  // drain DMA

#pragma unroll
    for (int ks = 0; ks < 2; ++ks) {
      const int cb = (ks << 2) + quad;
      bf16x8 fa[2], fb[4];
#pragma unroll
      for (int i = 0; i < 2; ++i)
        fa[i] = *(const bf16x8*)&S[0][wm + i * 16 + l16][(cb ^ (l16 & 7)) << 3];
#pragma unroll
      for (int j = 0; j < 4; ++j)
        fb[j] = *(const bf16x8*)&S[1][wn + j * 16 + l16][(cb ^ (l16 & 7)) << 3];
#pragma unroll
      for (int i = 0; i < 2; ++i)
#pragma unroll
        for (int j = 0; j < 4; ++j)
          acc[i][j] = __builtin_amdgcn_mfma_f32_16x16x32_bf16(fa[i], fb[j], acc[i][j], 0, 0, 0);
    }
    __syncthreads();  // all reads done before next overwrite
  }
  // After the final barrier the staging LDS is dead; each wave reuses its own 4 KB.

  if (n0 + wn >= 1280) {
    // V wave-tile: write transposed into vtg[(b*4+g)*64 + d][t] (uint2, proven path)
#pragma unroll
    for (int j = 0; j < 4; ++j) {
      const int gn = n0 + wn + j * 16 + l16;
      const float bias_v = bias[gn];
      const int dfull = gn - 1280;
      const int gg = dfull >> 6;
      const int dd = dfull & 63;
#pragma unroll
      for (int i = 0; i < 2; ++i) {
        const int gm = m0 + wm + i * 16 + quad * 4;  // 4 consecutive tokens
        const int bb = gm >> 11;
        const int tl = gm & 2047;
        __hip_bfloat16 tmp[4];
#pragma unroll
        for (int r = 0; r < 4; ++r) tmp[r] = __float2bfloat16(acc[i][j][r] + bias_v);
        *(uint2*)(vtg + ((size_t)((bb * 4 + gg) * 64 + dd)) * TT + tl) = *(const uint2*)tmp;
      }
    }
  } else {
    // Q/K wave-tile: LDS transpose -> coalesced 16B/lane stores
    __hip_bfloat16* scr = &S[0][0][0] + w * 2048;   // per-wave 32x64 bf16 (4 KB)
#pragma unroll
    for (int j = 0; j < 4; ++j) {
      const int gn = n0 + wn + j * 16 + l16;
      const float bias_v = bias[gn];
#pragma unroll
      for (int i = 0; i < 2; ++i)
#pragma unroll
        for (int r = 0; r < 4; ++r)
          scr[(i * 16 + quad * 4 + r) * 64 + j * 16 + l16] =
              __float2bfloat16(acc[i][j][r] + bias_v);
    }
    const int rrow = lane >> 3;          // 0..7
    const int rcol = (lane & 7) * 8;     // 0..56
#pragma unroll
    for (int s = 0; s < 4; ++s) {
      const int lr2 = s * 8 + rrow;      // 0..31
      const bf16x8 vv = *(const bf16x8*)&scr[lr2 * 64 + rcol];
      *(bf16x8*)(C + (size_t)(m0 + wm + lr2) * QKVD + (n0 + wn + rcol)) = vv;
    }
  }
}

// ---------------- gemm2: output projection, 64x128 tile, BK=64, single-buffer ------
// R4's proven form. [4096 x 1024] * [1024 x 1024]^T-packed -> fp32 out.
// grid (8, 64) = 512 blocks.

__global__ __launch_bounds__(256, 4) void k_gemm2(const __hip_bfloat16* __restrict__ A,
                                                  const __hip_bfloat16* __restrict__ BT,
                                                  const float* __restrict__ bias,
                                                  float* __restrict__ C) {
  __shared__ __hip_bfloat16 As[64][64];
  __shared__ __hip_bfloat16 Bs[128][64];

  const int tid  = threadIdx.x;
  const int m0   = blockIdx.y * 64;
  const int n0   = blockIdx.x * 128;
  const int w    = tid >> 6;
  const int lane = tid & 63;
  const int quad = lane >> 4;
  const int l16  = lane & 15;
  const int wm   = (w >> 1) * 32;
  const int wn   = (w & 1) * 64;

  const int dl_r = lane >> 3;
  const int dl_c = (lane & 7) ^ dl_r;

  const __hip_bfloat16* gA = A + (size_t)(m0 + w * 16 + dl_r) * 1024 + dl_c * 8;
  const __hip_bfloat16* gB = BT + (size_t)(n0 + w * 32 + dl_r) * 1024 + dl_c * 8;

  f32x4 acc[2][4] = {};

  for (int kt = 0; kt < 16; ++kt) {
    const int k0 = kt << 6;
    gload_lds16(gA + k0,                     &As[w * 16][0]);
    gload_lds16(gA + k0 + (size_t)8 * 1024,  &As[w * 16 + 8][0]);
    gload_lds16(gB + k0,                     &Bs[w * 32][0]);
    gload_lds16(gB + k0 + (size_t)8 * 1024,  &Bs[w * 32 + 8][0]);
    gload_lds16(gB + k0 + (size_t)16 * 1024, &Bs[w * 32 + 16][0]);
    gload_lds16(gB + k0 + (size_t)24 * 1024, &Bs[w * 32 + 24][0]);
    __syncthreads();

#pragma unroll
    for (int ks = 0; ks < 2; ++ks) {
      const int cb = (ks << 2) + quad;
      bf16x8 fa[2], fb[4];
#pragma unroll
      for (int i = 0; i < 2; ++i)
        fa[i] = *(const bf16x8*)&As[wm + i * 16 + l16][(cb ^ (l16 & 7)) << 3];
#pragma unroll
      for (int j = 0; j < 4; ++j)
        fb[j] = *(const bf16x8*)&Bs[wn + j * 16 + l16][(cb ^ (l16 & 7)) << 3];
#pragma unroll
      for (int i = 0; i < 2; ++i)
#pragma unroll
        for (int j = 0; j < 4; ++j)
          acc[i][j] = __builtin_amdgcn_mfma_f32_16x16x32_bf16(fa[i], fb[j], acc[i][j], 0, 0, 0);
    }
    __syncthreads();
  }

#pragma unroll
  for (int j = 0; j < 4; ++j) {
    const int gn = n0 + wn + j * 16 + l16;
    const float bias_v = bias[gn];
#pragma unroll
    for (int i = 0; i < 2; ++i) {
      const int gmb = m0 + wm + i * 16 + quad * 4;
#pragma unroll
      for (int r = 0; r < 4; ++r)
        C[(size_t)(gmb + r) * CC + gn] = acc[i][j][r] + bias_v;
    }
  }
}

// ---------------- MFMA flash attention v4: QBLK=128, 8 waves, 2x K/V reuse --------
// R4's proven structure. One K/V staging pass serves 128 q-rows; grid 512 blocks =
// 2/CU fully resident. Wave-group wg = w>>2 active for cc in [wg, 4+wg]; diagonal
// mask at cc==4+wg, window-tail mask at cc==wg; cc_lo = max(0, 4-2*bx).
// v7: coalesced y epilogue via per-wave Ps reuse (16 scalar 2B stores -> 2 dwordx4).

__global__ __launch_bounds__(512) void k_attn(const __hip_bfloat16* __restrict__ qkv,
                                              const __hip_bfloat16* __restrict__ vtg,
                                              __hip_bfloat16* __restrict__ y) {
  __shared__ __hip_bfloat16 Kb[2][64][64];  // [buf][key][d]   16 KB
  __shared__ __hip_bfloat16 Vb[2][64][64];  // [buf][d][key]   16 KB
  __shared__ __hip_bfloat16 Ps[8][16][72];  // per-wave P tile 18.4 KB

  const int t    = threadIdx.x;
  const int w    = t >> 6;      // 0..7
  const int lane = t & 63;
  const int quad = lane >> 4;
  const int l16  = lane & 15;
  const int bx   = blockIdx.x;  // 0..15
  const int h    = blockIdx.y;
  const int b    = blockIdx.z;
  const int g    = h >> 2;      // repeat_interleave: heads 4g..4g+3 -> group g
  const int i0   = bx * 128;
  const int wg   = w >> 2;      // wave-group: 0 = rows [i0,i0+64), 1 = [i0+64,i0+128)
  const int myq0 = i0 + w * 16;
  const int qrow      = myq0 + l16;
  const int my_q_base = myq0 + quad * 4;

  const int lrow = lane >> 3;
  const int cgl  = (lane & 7) ^ lrow;

  // wave w stages rows w*8 .. w*8+7 of each 64-row K/V chunk (1 gload each)
  const __hip_bfloat16* kg =
      qkv + ((size_t)(b * TT + w * 8 + lrow)) * QKVD + 1024 + g * 64 + cgl * 8;
  const __hip_bfloat16* vg =
      vtg + ((size_t)((b * 4 + g) * 64 + w * 8 + lrow)) * TT + cgl * 8;

  bf16x8 fq[2];
  {
    const __hip_bfloat16* qp = qkv + ((size_t)(b * TT + qrow)) * QKVD + h * 64 + quad * 8;
    fq[0] = *(const bf16x8*)qp;
    fq[1] = *(const bf16x8*)(qp + 32);
  }

  float l_r[4] = {0.f, 0.f, 0.f, 0.f};
  f32x4 o_acc[4] = {};
  const float EC = 0.125f * 1.44269504f;  // (1/sqrt(64)) * log2(e)

  const int cc_lo = bx >= 2 ? 0 : (4 - 2 * bx);
  const int jbase = i0 - 256;

  {
    const int jc = jbase + cc_lo * 64;
    gload_lds16(kg + (size_t)jc * QKVD, &Kb[0][w * 8][0]);
    gload_lds16(vg + jc,                &Vb[0][w * 8][0]);
  }

  int buf = 0;
  for (int cc = cc_lo; cc < 6; ++cc) {
    __syncthreads();
    if (cc < 5) {
      const int jn = jbase + (cc + 1) * 64;
      gload_lds16(kg + (size_t)jn * QKVD, &Kb[buf ^ 1][w * 8][0]);
      gload_lds16(vg + jn,                &Vb[buf ^ 1][w * 8][0]);
    }

    if (cc >= wg && cc <= 4 + wg) {   // this wave-group's 5-chunk window
      const int jc = jbase + cc * 64;

      f32x4 sacc[4] = {};
#pragma unroll
      for (int ks = 0; ks < 2; ++ks) {
        const int sw = (((ks << 2) + quad) ^ (l16 & 7)) << 3;
#pragma unroll
        for (int nt = 0; nt < 4; ++nt) {
          const bf16x8 fk = *(const bf16x8*)&Kb[buf][nt * 16 + l16][sw];
          sacc[nt] = __builtin_amdgcn_mfma_f32_16x16x32_bf16(fq[ks], fk, sacc[nt], 0, 0, 0);
        }
      }

      // p = exp(s/8); mask only where needed (wave-uniform chunk classification)
      if (cc == 4 + wg) {        // diagonal: key <= i
#pragma unroll
        for (int r = 0; r < 4; ++r) {
          const int gi = my_q_base + r;
#pragma unroll
          for (int nt = 0; nt < 4; ++nt) {
            const int key = jc + nt * 16 + l16;
            const float p = (key <= gi) ? exp2f(sacc[nt][r] * EC) : 0.f;
            l_r[r] += p;
            Ps[w][quad * 4 + r][nt * 16 + l16] = __float2bfloat16(p);
          }
        }
      } else if (cc == wg) {     // window tail: key >= i - 256 (only reachable when jc>=0)
#pragma unroll
        for (int r = 0; r < 4; ++r) {
          const int glo = my_q_base + r - 256;
#pragma unroll
          for (int nt = 0; nt < 4; ++nt) {
            const int key = jc + nt * 16 + l16;
            const float p = (key >= glo) ? exp2f(sacc[nt][r] * EC) : 0.f;
            l_r[r] += p;
            Ps[w][quad * 4 + r][nt * 16 + l16] = __float2bfloat16(p);
          }
        }
      } else {                   // interior: mask-free
#pragma unroll
        for (int r = 0; r < 4; ++r)
#pragma unroll
          for (int nt = 0; nt < 4; ++nt) {
            const float p = exp2f(sacc[nt][r] * EC);
            l_r[r] += p;
            Ps[w][quad * 4 + r][nt * 16 + l16] = __float2bfloat16(p);
          }
      }

      const bf16x8 fp0 = *(const bf16x8*)&Ps[w][l16][quad * 8];
      const bf16x8 fp1 = *(const bf16x8*)&Ps[w][l16][32 + quad * 8];

#pragma unroll
      for (int ks = 0; ks < 2; ++ks) {
        const int sw = (((ks << 2) + quad) ^ (l16 & 7)) << 3;
#pragma unroll
        for (int jt = 0; jt < 4; ++jt) {
          const bf16x8 fv = *(const bf16x8*)&Vb[buf][jt * 16 + l16][sw];
          o_acc[jt] = __builtin_amdgcn_mfma_f32_16x16x32_bf16(ks == 0 ? fp0 : fp1, fv,
                                                              o_acc[jt], 0, 0, 0);
        }
      }
    }
    buf ^= 1;
  }

  // epilogue: normalize, transpose through the per-wave Ps tile (dead after the
  // loop, intra-wave ordering only), then 16B/lane coalesced stores.
#pragma unroll
  for (int r = 0; r < 4; ++r) {
#pragma unroll
    for (int d = 1; d < 16; d <<= 1) l_r[r] += __shfl_xor(l_r[r], d);
    const float inv = 1.f / l_r[r];
#pragma unroll
    for (int jt = 0; jt < 4; ++jt)
      Ps[w][quad * 4 + r][jt * 16 + l16] = __float2bfloat16(o_acc[jt][r] * inv);
  }
  const int rrow = lane >> 3;        // 0..7
  const int rcol = (lane & 7) * 8;   // 0..56
#pragma unroll
  for (int s = 0; s < 2; ++s) {
    const int qr = s * 8 + rrow;     // 0..15
    const bf16x8 vv = *(const bf16x8*)&Ps[w][qr][rcol];
    *(bf16x8*)(y + ((size_t)(b * TT + myq0 + qr)) * CC + h * 64 + rcol) = vv;
  }
}

// ---------------- launch ----------------

extern "C" void kernel_launch(void* const* d_in, const int* in_sizes, int n_in,
                              void* d_out, int out_size, void* d_ws, size_t ws_size,
                              hipStream_t stream) {
  const float* x  = (const float*)d_in[0];
  const float* Wq = (const float*)d_in[1];
  const float* bq = (const float*)d_in[2];
  const float* Wk = (const float*)d_in[3];
  const float* bk = (const float*)d_in[4];
  const float* Wv = (const float*)d_in[5];
  const float* bv = (const float*)d_in[6];
  const float* Wo = (const float*)d_in[7];
  const float* bo = (const float*)d_in[8];
  float* out = (float*)d_out;

  char* ws = (char*)d_ws;
  const size_t M = 2 * TT;  // 4096
  __hip_bfloat16* xbf   = (__hip_bfloat16*)(ws);               // 8 MB
  __hip_bfloat16* qkv   = (__hip_bfloat16*)(ws + 8388608);     // 12 MB (V region unused)
  __hip_bfloat16* ybf   = (__hip_bfloat16*)(ws + 20971520);    // 8 MB
  __hip_bfloat16* wqkvT = (__hip_bfloat16*)(ws + 29360128);    // 3 MB
  __hip_bfloat16* woT   = (__hip_bfloat16*)(ws + 32505856);    // 2 MB
  float*          bqkv  = (float*)(ws + 34603008);             // 6 KB
  __hip_bfloat16* vtg   = (__hip_bfloat16*)(ws + 34609152);    // 2 MB

  // prep: x convert (4096) + wqkv pack (384) + wo pack (256) + bias (1)
  k_prep<<<4737, 256, 0, stream>>>(x, Wq, Wk, Wv, Wo, bq, bk, bv,
                                   xbf, wqkvT, woT, bqkv);

  // QKV projection: 128x128 tiles, 8-wave blocks, grid (12, 32)
  k_gemm1<<<dim3(QKVD / 128, M / 128), 512, 0, stream>>>(xbf, wqkvT, bqkv, qkv, vtg);

  // attention: 512 blocks of 512 threads (8 waves, QBLK=128)
  k_attn<<<dim3(TT / 128, 16, 2), 512, 0, stream>>>(qkv, vtg, ybf);

  // output projection: 64x128 tiles, 4-wave blocks, grid (8, 64) -> fp32
  k_gemm2<<<dim3(CC / 128, M / 64), 256, 0, stream>>>(ybf, woT, bo, out);
}

// Round 8
// 141.888 us; speedup vs baseline: 1.0476x; 1.0061x over previous
//
#include <hip/hip_runtime.h>
#include <hip/hip_bf16.h>

// Problem constants (B=2, T=2048, C=1024, H=16, G=4, hd=64, KV=256, WINDOW=256)
#define TT 2048
#define CC 1024
#define KVD 256
#define QKVD 1536

typedef __bf16 bf16x8 __attribute__((ext_vector_type(8)));
typedef float f32x4 __attribute__((ext_vector_type(4)));

// async global->LDS, 16B per lane. LDS dest is wave-uniform base + lane*16 (HW rule).
__device__ __forceinline__ void gload_lds16(const __hip_bfloat16* g, __hip_bfloat16* l) {
  __builtin_amdgcn_global_load_lds(
      (const __attribute__((address_space(1))) unsigned int*)g,
      (__attribute__((address_space(3))) unsigned int*)l, 16, 0, 0);
}

// ---------------- merged prep: x->bf16 convert + weight packs + bias ----------------
// 1D grid: [0,4096) convert x; [4096,4480) pack wqkvT; [4480,4736) pack woT; [4736] bias.

__global__ __launch_bounds__(256) void k_prep(const float* __restrict__ x,
                                              const float* __restrict__ Wq,
                                              const float* __restrict__ Wk,
                                              const float* __restrict__ Wv,
                                              const float* __restrict__ Wo,
                                              const float* __restrict__ bq,
                                              const float* __restrict__ bk,
                                              const float* __restrict__ bv,
                                              __hip_bfloat16* __restrict__ xbf,
                                              __hip_bfloat16* __restrict__ wqkvT,
                                              __hip_bfloat16* __restrict__ woT,
                                              float* __restrict__ bqkv) {
  const int bxid = blockIdx.x;
  if (bxid < 4096) {
    size_t idx = ((size_t)bxid * 256 + threadIdx.x) * 4;
    float4 v = *(const float4*)(x + idx);
    xbf[idx + 0] = __float2bfloat16(v.x);
    xbf[idx + 1] = __float2bfloat16(v.y);
    xbf[idx + 2] = __float2bfloat16(v.z);
    xbf[idx + 3] = __float2bfloat16(v.w);
    return;
  }
  if (bxid == 4736) {
    for (int i = threadIdx.x; i < 1536; i += 256) {
      float v;
      if (i < 1024)      v = bq[i];
      else if (i < 1280) v = bk[i - 1024];
      else               v = bv[i - 1280];
      bqkv[i] = v;
    }
    return;
  }
  // weight pack via LDS tile transpose, coalesced both sides
  __shared__ float tile[64][65];
  const float* src;
  int ncols, k0, n0;
  __hip_bfloat16* dst;
  if (bxid < 4480) {
    const int idx = bxid - 4096;          // 384 tiles: 16 k x 24 n
    k0 = (idx & 15) * 64;
    n0 = (idx >> 4) * 64;
    dst = wqkvT;
    if (n0 < 1024)      { src = Wq; ncols = 1024; }
    else if (n0 < 1280) { src = Wk - 1024; ncols = 256; }
    else                { src = Wv - 1280; ncols = 256; }
  } else {
    const int idx = bxid - 4480;          // 256 tiles: 16 k x 16 n
    k0 = (idx & 15) * 64;
    n0 = (idx >> 4) * 64;
    dst = woT; src = Wo; ncols = 1024;
  }
  const int rw = threadIdx.x >> 6;
  const int cl = threadIdx.x & 63;
#pragma unroll
  for (int i = 0; i < 16; ++i) {
    const int kr = rw + i * 4;
    tile[kr][cl] = src[(size_t)(k0 + kr) * ncols + n0 + cl];
  }
  __syncthreads();
#pragma unroll
  for (int i = 0; i < 16; ++i) {
    const int nr = rw + i * 4;
    dst[(size_t)(n0 + nr) * 1024 + k0 + cl] = __float2bfloat16(tile[cl][nr]);
  }
}

// ---------------- gemm1: QKV projection, 128x128 tile, BK=64, 8 waves -------------
// K-loop: proven single-buffer 2-barrier form. Coalesced Q/K epilogue via per-wave
// LDS transpose; V columns (wave-uniform) keep the transposed vtg uint2 path.
// grid (12, 32).

__global__ __launch_bounds__(512, 4) void k_gemm1(const __hip_bfloat16* __restrict__ A,
                                                  const __hip_bfloat16* __restrict__ BT,
                                                  const float* __restrict__ bias,
                                                  __hip_bfloat16* __restrict__ C,
                                                  __hip_bfloat16* __restrict__ vtg) {
  __shared__ __hip_bfloat16 S[2][128][64];   // S[0]=As, S[1]=Bs, 32 KB contiguous

  const int tid  = threadIdx.x;
  const int m0   = blockIdx.y * 128;
  const int n0   = blockIdx.x * 128;
  const int w    = tid >> 6;               // 0..7
  const int lane = tid & 63;
  const int quad = lane >> 4;
  const int l16  = lane & 15;
  const int wm   = (w & 3) * 32;           // 4 row-groups of 32
  const int wn   = (w >> 2) * 64;          // 2 col-groups of 64

  const int dl_r = lane >> 3;               // 0..7
  const int dl_c = (lane & 7) ^ dl_r;       // swizzled global 16B chunk

  // wave w stages A rows [w*16, w*16+16) and B rows [w*16, w*16+16)
  const __hip_bfloat16* gA = A + (size_t)(m0 + w * 16 + dl_r) * 1024 + dl_c * 8;
  const __hip_bfloat16* gB = BT + (size_t)(n0 + w * 16 + dl_r) * 1024 + dl_c * 8;

  f32x4 acc[2][4] = {};

  for (int kt = 0; kt < 16; ++kt) {
    const int k0 = kt << 6;
    gload_lds16(gA + k0,                    &S[0][w * 16][0]);
    gload_lds16(gA + k0 + (size_t)8 * 1024, &S[0][w * 16 + 8][0]);
    gload_lds16(gB + k0,                    &S[1][w * 16][0]);
    gload_lds16(gB + k0 + (size_t)8 * 1024, &S[1][w * 16 + 8][0]);
    __syncthreads();  // drain DMA

#pragma unroll
    for (int ks = 0; ks < 2; ++ks) {
      const int cb = (ks << 2) + quad;
      bf16x8 fa[2], fb[4];
#pragma unroll
      for (int i = 0; i < 2; ++i)
        fa[i] = *(const bf16x8*)&S[0][wm + i * 16 + l16][(cb ^ (l16 & 7)) << 3];
#pragma unroll
      for (int j = 0; j < 4; ++j)
        fb[j] = *(const bf16x8*)&S[1][wn + j * 16 + l16][(cb ^ (l16 & 7)) << 3];
#pragma unroll
      for (int i = 0; i < 2; ++i)
#pragma unroll
        for (int j = 0; j < 4; ++j)
          acc[i][j] = __builtin_amdgcn_mfma_f32_16x16x32_bf16(fa[i], fb[j], acc[i][j], 0, 0, 0);
    }
    __syncthreads();  // all reads done before next overwrite
  }
  // After the final barrier the staging LDS is dead; each wave reuses its own 4 KB.

  if (n0 + wn >= 1280) {
    // V wave-tile: write transposed into vtg[(b*4+g)*64 + d][t] (uint2, proven path)
#pragma unroll
    for (int j = 0; j < 4; ++j) {
      const int gn = n0 + wn + j * 16 + l16;
      const float bias_v = bias[gn];
      const int dfull = gn - 1280;
      const int gg = dfull >> 6;
      const int dd = dfull & 63;
#pragma unroll
      for (int i = 0; i < 2; ++i) {
        const int gm = m0 + wm + i * 16 + quad * 4;  // 4 consecutive tokens
        const int bb = gm >> 11;
        const int tl = gm & 2047;
        __hip_bfloat16 tmp[4];
#pragma unroll
        for (int r = 0; r < 4; ++r) tmp[r] = __float2bfloat16(acc[i][j][r] + bias_v);
        *(uint2*)(vtg + ((size_t)((bb * 4 + gg) * 64 + dd)) * TT + tl) = *(const uint2*)tmp;
      }
    }
  } else {
    // Q/K wave-tile: LDS transpose -> coalesced 16B/lane stores
    __hip_bfloat16* scr = &S[0][0][0] + w * 2048;   // per-wave 32x64 bf16 (4 KB)
#pragma unroll
    for (int j = 0; j < 4; ++j) {
      const int gn = n0 + wn + j * 16 + l16;
      const float bias_v = bias[gn];
#pragma unroll
      for (int i = 0; i < 2; ++i)
#pragma unroll
        for (int r = 0; r < 4; ++r)
          scr[(i * 16 + quad * 4 + r) * 64 + j * 16 + l16] =
              __float2bfloat16(acc[i][j][r] + bias_v);
    }
    const int rrow = lane >> 3;          // 0..7
    const int rcol = (lane & 7) * 8;     // 0..56
#pragma unroll
    for (int s = 0; s < 4; ++s) {
      const int lr2 = s * 8 + rrow;      // 0..31
      const bf16x8 vv = *(const bf16x8*)&scr[lr2 * 64 + rcol];
      *(bf16x8*)(C + (size_t)(m0 + wm + lr2) * QKVD + (n0 + wn + rcol)) = vv;
    }
  }
}

// ---------------- gemm2: output projection, 64x128 tile, BK=64, single-buffer ------
// Proven form. [4096 x 1024] * [1024 x 1024]^T-packed -> fp32 out. grid (8, 64).

__global__ __launch_bounds__(256, 4) void k_gemm2(const __hip_bfloat16* __restrict__ A,
                                                  const __hip_bfloat16* __restrict__ BT,
                                                  const float* __restrict__ bias,
                                                  float* __restrict__ C) {
  __shared__ __hip_bfloat16 As[64][64];
  __shared__ __hip_bfloat16 Bs[128][64];

  const int tid  = threadIdx.x;
  const int m0   = blockIdx.y * 64;
  const int n0   = blockIdx.x * 128;
  const int w    = tid >> 6;
  const int lane = tid & 63;
  const int quad = lane >> 4;
  const int l16  = lane & 15;
  const int wm   = (w >> 1) * 32;
  const int wn   = (w & 1) * 64;

  const int dl_r = lane >> 3;
  const int dl_c = (lane & 7) ^ dl_r;

  const __hip_bfloat16* gA = A + (size_t)(m0 + w * 16 + dl_r) * 1024 + dl_c * 8;
  const __hip_bfloat16* gB = BT + (size_t)(n0 + w * 32 + dl_r) * 1024 + dl_c * 8;

  f32x4 acc[2][4] = {};

  for (int kt = 0; kt < 16; ++kt) {
    const int k0 = kt << 6;
    gload_lds16(gA + k0,                     &As[w * 16][0]);
    gload_lds16(gA + k0 + (size_t)8 * 1024,  &As[w * 16 + 8][0]);
    gload_lds16(gB + k0,                     &Bs[w * 32][0]);
    gload_lds16(gB + k0 + (size_t)8 * 1024,  &Bs[w * 32 + 8][0]);
    gload_lds16(gB + k0 + (size_t)16 * 1024, &Bs[w * 32 + 16][0]);
    gload_lds16(gB + k0 + (size_t)24 * 1024, &Bs[w * 32 + 24][0]);
    __syncthreads();

#pragma unroll
    for (int ks = 0; ks < 2; ++ks) {
      const int cb = (ks << 2) + quad;
      bf16x8 fa[2], fb[4];
#pragma unroll
      for (int i = 0; i < 2; ++i)
        fa[i] = *(const bf16x8*)&As[wm + i * 16 + l16][(cb ^ (l16 & 7)) << 3];
#pragma unroll
      for (int j = 0; j < 4; ++j)
        fb[j] = *(const bf16x8*)&Bs[wn + j * 16 + l16][(cb ^ (l16 & 7)) << 3];
#pragma unroll
      for (int i = 0; i < 2; ++i)
#pragma unroll
        for (int j = 0; j < 4; ++j)
          acc[i][j] = __builtin_amdgcn_mfma_f32_16x16x32_bf16(fa[i], fb[j], acc[i][j], 0, 0, 0);
    }
    __syncthreads();
  }

#pragma unroll
  for (int j = 0; j < 4; ++j) {
    const int gn = n0 + wn + j * 16 + l16;
    const float bias_v = bias[gn];
#pragma unroll
    for (int i = 0; i < 2; ++i) {
      const int gmb = m0 + wm + i * 16 + quad * 4;
#pragma unroll
      for (int r = 0; r < 4; ++r)
        C[(size_t)(gmb + r) * CC + gn] = acc[i][j][r] + bias_v;
    }
  }
}

// ---------------- MFMA flash attention v5: QBLK=128 + wave-uniform mask skip -------
// R4 structure + skip of fully-masked MFMA blocks. For wave sub-index ws = w&3:
//   diagonal chunk (cc==4+wg): keys nt*16.. are all > every q-row when nt > ws
//     -> QK^T computes nt <= ws only; PV ks=1 (keys 32-63) dead when ws <= 1.
//   tail chunk (cc==wg): keys nt*16.. all < window when nt < ws
//     -> QK^T computes nt >= ws only; PV ks=0 (keys 0-31) dead when ws >= 2.
// All conditions wave-uniform -> exec-mask branch, no divergence. The at-most-one
// Ps nt-block read by an active PV half but skipped in QK^T is zeroed explicitly.
// Per-wave MFMA: 80 -> 70 (-12.5%), matching ds_read + exp2f savings.

__global__ __launch_bounds__(512) void k_attn(const __hip_bfloat16* __restrict__ qkv,
                                              const __hip_bfloat16* __restrict__ vtg,
                                              __hip_bfloat16* __restrict__ y) {
  __shared__ __hip_bfloat16 Kb[2][64][64];  // [buf][key][d]   16 KB
  __shared__ __hip_bfloat16 Vb[2][64][64];  // [buf][d][key]   16 KB
  __shared__ __hip_bfloat16 Ps[8][16][72];  // per-wave P tile 18.4 KB

  const int t    = threadIdx.x;
  const int w    = t >> 6;      // 0..7
  const int lane = t & 63;
  const int quad = lane >> 4;
  const int l16  = lane & 15;
  const int bx   = blockIdx.x;  // 0..15
  const int h    = blockIdx.y;
  const int b    = blockIdx.z;
  const int g    = h >> 2;      // repeat_interleave: heads 4g..4g+3 -> group g
  const int i0   = bx * 128;
  const int wg   = w >> 2;      // wave-group: 0 = rows [i0,i0+64), 1 = [i0+64,i0+128)
  const int ws   = w & 3;       // sub-index within wave-group (16-row slice)
  const int myq0 = i0 + w * 16;
  const int qrow      = myq0 + l16;
  const int my_q_base = myq0 + quad * 4;

  const int lrow = lane >> 3;
  const int cgl  = (lane & 7) ^ lrow;

  // wave w stages rows w*8 .. w*8+7 of each 64-row K/V chunk (1 gload each)
  const __hip_bfloat16* kg =
      qkv + ((size_t)(b * TT + w * 8 + lrow)) * QKVD + 1024 + g * 64 + cgl * 8;
  const __hip_bfloat16* vg =
      vtg + ((size_t)((b * 4 + g) * 64 + w * 8 + lrow)) * TT + cgl * 8;

  bf16x8 fq[2];
  {
    const __hip_bfloat16* qp = qkv + ((size_t)(b * TT + qrow)) * QKVD + h * 64 + quad * 8;
    fq[0] = *(const bf16x8*)qp;
    fq[1] = *(const bf16x8*)(qp + 32);
  }

  float l_r[4] = {0.f, 0.f, 0.f, 0.f};
  f32x4 o_acc[4] = {};
  const float EC = 0.125f * 1.44269504f;  // (1/sqrt(64)) * log2(e)

  const int cc_lo = bx >= 2 ? 0 : (4 - 2 * bx);
  const int jbase = i0 - 256;

  {
    const int jc = jbase + cc_lo * 64;
    gload_lds16(kg + (size_t)jc * QKVD, &Kb[0][w * 8][0]);
    gload_lds16(vg + jc,                &Vb[0][w * 8][0]);
  }

  int buf = 0;
  for (int cc = cc_lo; cc < 6; ++cc) {
    __syncthreads();
    if (cc < 5) {
      const int jn = jbase + (cc + 1) * 64;
      gload_lds16(kg + (size_t)jn * QKVD, &Kb[buf ^ 1][w * 8][0]);
      gload_lds16(vg + jn,                &Vb[buf ^ 1][w * 8][0]);
    }

    if (cc >= wg && cc <= 4 + wg) {   // this wave-group's 5-chunk window
      const int jc = jbase + cc * 64;
      const int ctype = (cc == 4 + wg) ? 1 : ((cc == wg) ? 2 : 0);  // 1=diag 2=tail
      const int nt_lo_c = (ctype == 2) ? ws : 0;
      const int nt_hi_c = (ctype == 1) ? ws : 3;
      const bool pv0 = !(ctype == 2 && ws >= 2);   // keys 0-31 half
      const bool pv1 = !(ctype == 1 && ws <= 1);   // keys 32-63 half

      // QK^T: only nt blocks with at least one unmasked key for this wave
      f32x4 sacc[4] = {};
#pragma unroll
      for (int nt = 0; nt < 4; ++nt) {
        if (nt >= nt_lo_c && nt <= nt_hi_c) {
#pragma unroll
          for (int ks = 0; ks < 2; ++ks) {
            const int sw = (((ks << 2) + quad) ^ (l16 & 7)) << 3;
            const bf16x8 fk = *(const bf16x8*)&Kb[buf][nt * 16 + l16][sw];
            sacc[nt] = __builtin_amdgcn_mfma_f32_16x16x32_bf16(fq[ks], fk, sacc[nt], 0, 0, 0);
          }
        }
      }

      // p = exp(s/8) over computed nt range; per-element mask on boundary blocks
      if (ctype == 1) {          // diagonal: key <= i
#pragma unroll
        for (int r = 0; r < 4; ++r) {
          const int gi = my_q_base + r;
#pragma unroll
          for (int nt = 0; nt < 4; ++nt) {
            if (nt <= nt_hi_c) {
              const int key = jc + nt * 16 + l16;
              const float p = (key <= gi) ? exp2f(sacc[nt][r] * EC) : 0.f;
              l_r[r] += p;
              Ps[w][quad * 4 + r][nt * 16 + l16] = __float2bfloat16(p);
            }
          }
        }
      } else if (ctype == 2) {   // window tail: key >= i - 256
#pragma unroll
        for (int r = 0; r < 4; ++r) {
          const int glo = my_q_base + r - 256;
#pragma unroll
          for (int nt = 0; nt < 4; ++nt) {
            if (nt >= nt_lo_c) {
              const int key = jc + nt * 16 + l16;
              const float p = (key >= glo) ? exp2f(sacc[nt][r] * EC) : 0.f;
              l_r[r] += p;
              Ps[w][quad * 4 + r][nt * 16 + l16] = __float2bfloat16(p);
            }
          }
        }
      } else {                   // interior: mask-free
#pragma unroll
        for (int r = 0; r < 4; ++r)
#pragma unroll
          for (int nt = 0; nt < 4; ++nt) {
            const float p = exp2f(sacc[nt][r] * EC);
            l_r[r] += p;
            Ps[w][quad * 4 + r][nt * 16 + l16] = __float2bfloat16(p);
          }
      }

      // zero the Ps nt-blocks an active PV half reads but QK^T skipped
#pragma unroll
      for (int nt = 0; nt < 4; ++nt) {
        const bool computed = (nt >= nt_lo_c && nt <= nt_hi_c);
        const bool needed = (nt < 2) ? pv0 : pv1;
        if (needed && !computed) {
#pragma unroll
          for (int r = 0; r < 4; ++r)
            Ps[w][quad * 4 + r][nt * 16 + l16] = __float2bfloat16(0.f);
        }
      }

      // PV: skip dead key-halves
      if (pv0) {
        const bf16x8 fp0 = *(const bf16x8*)&Ps[w][l16][quad * 8];
        const int sw = (quad ^ (l16 & 7)) << 3;               // cb = 0*4 + quad
#pragma unroll
        for (int jt = 0; jt < 4; ++jt) {
          const bf16x8 fv = *(const bf16x8*)&Vb[buf][jt * 16 + l16][sw];
          o_acc[jt] = __builtin_amdgcn_mfma_f32_16x16x32_bf16(fp0, fv, o_acc[jt], 0, 0, 0);
        }
      }
      if (pv1) {
        const bf16x8 fp1 = *(const bf16x8*)&Ps[w][l16][32 + quad * 8];
        const int sw = ((4 + quad) ^ (l16 & 7)) << 3;         // cb = 1*4 + quad
#pragma unroll
        for (int jt = 0; jt < 4; ++jt) {
          const bf16x8 fv = *(const bf16x8*)&Vb[buf][jt * 16 + l16][sw];
          o_acc[jt] = __builtin_amdgcn_mfma_f32_16x16x32_bf16(fp1, fv, o_acc[jt], 0, 0, 0);
        }
      }
    }
    buf ^= 1;
  }

  // epilogue: normalize, transpose through the per-wave Ps tile, coalesced stores
#pragma unroll
  for (int r = 0; r < 4; ++r) {
#pragma unroll
    for (int d = 1; d < 16; d <<= 1) l_r[r] += __shfl_xor(l_r[r], d);
    const float inv = 1.f / l_r[r];
#pragma unroll
    for (int jt = 0; jt < 4; ++jt)
      Ps[w][quad * 4 + r][jt * 16 + l16] = __float2bfloat16(o_acc[jt][r] * inv);
  }
  const int rrow = lane >> 3;        // 0..7
  const int rcol = (lane & 7) * 8;   // 0..56
#pragma unroll
  for (int s = 0; s < 2; ++s) {
    const int qr = s * 8 + rrow;     // 0..15
    const bf16x8 vv = *(const bf16x8*)&Ps[w][qr][rcol];
    *(bf16x8*)(y + ((size_t)(b * TT + myq0 + qr)) * CC + h * 64 + rcol) = vv;
  }
}

// ---------------- launch ----------------

extern "C" void kernel_launch(void* const* d_in, const int* in_sizes, int n_in,
                              void* d_out, int out_size, void* d_ws, size_t ws_size,
                              hipStream_t stream) {
  const float* x  = (const float*)d_in[0];
  const float* Wq = (const float*)d_in[1];
  const float* bq = (const float*)d_in[2];
  const float* Wk = (const float*)d_in[3];
  const float* bk = (const float*)d_in[4];
  const float* Wv = (const float*)d_in[5];
  const float* bv = (const float*)d_in[6];
  const float* Wo = (const float*)d_in[7];
  const float* bo = (const float*)d_in[8];
  float* out = (float*)d_out;

  char* ws = (char*)d_ws;
  const size_t M = 2 * TT;  // 4096
  __hip_bfloat16* xbf   = (__hip_bfloat16*)(ws);               // 8 MB
  __hip_bfloat16* qkv   = (__hip_bfloat16*)(ws + 8388608);     // 12 MB (V region unused)
  __hip_bfloat16* ybf   = (__hip_bfloat16*)(ws + 20971520);    // 8 MB
  __hip_bfloat16* wqkvT = (__hip_bfloat16*)(ws + 29360128);    // 3 MB
  __hip_bfloat16* woT   = (__hip_bfloat16*)(ws + 32505856);    // 2 MB
  float*          bqkv  = (float*)(ws + 34603008);             // 6 KB
  __hip_bfloat16* vtg   = (__hip_bfloat16*)(ws + 34609152);    // 2 MB

  // prep: x convert (4096) + wqkv pack (384) + wo pack (256) + bias (1)
  k_prep<<<4737, 256, 0, stream>>>(x, Wq, Wk, Wv, Wo, bq, bk, bv,
                                   xbf, wqkvT, woT, bqkv);

  // QKV projection: 128x128 tiles, 8-wave blocks, grid (12, 32)
  k_gemm1<<<dim3(QKVD / 128, M / 128), 512, 0, stream>>>(xbf, wqkvT, bqkv, qkv, vtg);

  // attention: 512 blocks of 512 threads (8 waves, QBLK=128, mask-skip)
  k_attn<<<dim3(TT / 128, 16, 2), 512, 0, stream>>>(qkv, vtg, ybf);

  // output projection: 64x128 tiles, 4-wave blocks, grid (8, 64) -> fp32
  k_gemm2<<<dim3(CC / 128, M / 64), 256, 0, stream>>>(ybf, woT, bo, out);
}